// Round 4
// baseline (159.325 us; speedup 1.0000x reference)
//
#include <hip/hip_runtime.h>
#include <hip/hip_cooperative_groups.h>
#include <math.h>

namespace cg = cooperative_groups;

#define NNODES   8192
#define NODE_NUM 256
#define MAX_DEG  16
#define N_FEAT   128
#define N_HID    256
#define N_CLASS  64

typedef __attribute__((ext_vector_type(8))) short bf16x8;
typedef __attribute__((ext_vector_type(4))) float f32x4;

// f32 -> bf16 round-to-nearest-even
static __device__ __forceinline__ short f2b(float f) {
    unsigned u = __float_as_uint(f);
    unsigned r = (u + 0x7fffu + ((u >> 16) & 1u)) >> 16;
    return (short)r;
}

// ---------------------------------------------------------------------------
// Single cooperative kernel. 256 blocks x 512 threads (1 block/CU).
//   Phase A: masks (LDS) + W->bf16 transpose (grid-strided) + x gather->LDS
//   grid.sync()
//   Phase B: MFMA GEMM1+relu (LDS) ; MFMA GEMM2 -> t2 f32 (global ws)
//   grid.sync()
//   Phase C: adjacency gather of t2 + wave log-softmax -> out
// MFMA 16x16x32 bf16 layouts (verified in R3, absmax 2.0):
//   A: lane l holds A[row=l&15][k=8*(l>>4)+j]
//   B: lane l holds B[k=8*(l>>4)+j][col=l&15]
//   C: reg r -> row=(l>>4)*4+r, col=l&15
// ---------------------------------------------------------------------------
__global__ __launch_bounds__(512) void k_all(const float* __restrict__ x,
                                             const int* __restrict__ edge,
                                             const float* __restrict__ W1,
                                             const float* __restrict__ W2,
                                             short* __restrict__ W1T,
                                             short* __restrict__ W2T,
                                             float* __restrict__ t2,
                                             float* __restrict__ out) {
    __shared__ unsigned int mk[32];
    __shared__ short agg[32 * 136];   // [32][128+8] bf16
    __shared__ short hb[32 * 264];    // [32][256+8] bf16

    const int bid  = blockIdx.x;
    const int work = (bid & 7) * 32 + (bid >> 3);   // XCD-swizzled work id
    const int row0 = work * 32;
    const int t    = threadIdx.x;

    // ---- phase A0: dedup/validity mask for this block's 32 nodes ----
    if (t < 32) {
        const int* e = edge + (size_t)(row0 + t) * MAX_DEG;
        int ids[MAX_DEG];
#pragma unroll
        for (int k = 0; k < MAX_DEG; ++k) ids[k] = e[k];
        unsigned int m = 0;
#pragma unroll
        for (int k = 0; k < MAX_DEG; ++k) {
            bool skip = (ids[k] == -1);
#pragma unroll
            for (int l = 0; l < k; ++l) skip = skip || (ids[l] == ids[k]);
            if (!skip) m |= (1u << k);
        }
        mk[t] = m;
    }

    // ---- phase A1: weight transpose+convert, grid-strided (once per call) ----
    {
        const int g = bid * 512 + t;                 // 0..131071
        if (g < 32768) {                             // W1T[n*128+k] = W1[k*256+n]
            const int n = g >> 7, k = g & 127;
            W1T[g] = f2b(W1[k * N_HID + n]);
        } else if (g < 49152) {                      // W2T[n*256+k] = W2[k*64+n]
            const int g2 = g - 32768;
            const int n = g2 >> 8, k = g2 & 255;
            W2T[g2] = f2b(W2[k * N_CLASS + n]);
        }
    }
    __syncthreads();

    // ---- phase A2: gather-aggregate x rows -> agg LDS (bf16) ----
    {
        const int r = t >> 4;                        // local row 0..31
        const int c = t & 15;                        // 8-float chunk
        const int node = row0 + r;
        const int base = node & ~(NODE_NUM - 1);
        const int* e = edge + (size_t)node * MAX_DEG;
        const unsigned int m = mk[r];
        float a[8] = {0, 0, 0, 0, 0, 0, 0, 0};
#pragma unroll
        for (int k = 0; k < MAX_DEG; ++k) {
            if (m & (1u << k)) {
                const float* rowp = x + (size_t)(base + e[k]) * N_FEAT + c * 8;
                float4 v0 = *(const float4*)(rowp);
                float4 v1 = *(const float4*)(rowp + 4);
                a[0] += v0.x; a[1] += v0.y; a[2] += v0.z; a[3] += v0.w;
                a[4] += v1.x; a[5] += v1.y; a[6] += v1.z; a[7] += v1.w;
            }
        }
        bf16x8 p;
#pragma unroll
        for (int j = 0; j < 8; ++j) p[j] = f2b(a[j]);
        *(bf16x8*)(&agg[r * 136 + c * 8]) = p;
    }

    cg::this_grid().sync();   // W1T/W2T visible device-wide; agg ready in-block

    const int w   = t >> 6;                          // wave 0..7
    const int l   = t & 63;
    const int l16 = l & 15, l4 = l >> 4;

    // ---- phase B1: h = relu(agg @ W1)  [32x128]x[128x256] ----
    {
        const int mt = w >> 2;                       // M-tile 0..1
        bf16x8 afrag[4];
#pragma unroll
        for (int k4 = 0; k4 < 4; ++k4)
            afrag[k4] = *(const bf16x8*)(&agg[(mt * 16 + l16) * 136 + k4 * 32 + l4 * 8]);
#pragma unroll
        for (int n = 0; n < 4; ++n) {
            const int nt = (w & 3) * 4 + n;          // N-tile 0..15
            f32x4 acc = {0.f, 0.f, 0.f, 0.f};
#pragma unroll
            for (int k4 = 0; k4 < 4; ++k4) {
                bf16x8 b = *(const bf16x8*)(W1T + (nt * 16 + l16) * 128 + k4 * 32 + l4 * 8);
                acc = __builtin_amdgcn_mfma_f32_16x16x32_bf16(afrag[k4], b, acc, 0, 0, 0);
            }
#pragma unroll
            for (int r = 0; r < 4; ++r) {
                const int rr = mt * 16 + l4 * 4 + r;
                hb[rr * 264 + nt * 16 + l16] = f2b(fmaxf(acc[r], 0.f));
            }
        }
    }
    __syncthreads();

    // ---- phase B2: t2 = h @ W2  [32x256]x[256x64] ----
    {
        const int mt = w >> 2, nt = w & 3;           // 2M x 4N wave tiles
        f32x4 acc = {0.f, 0.f, 0.f, 0.f};
#pragma unroll
        for (int k8 = 0; k8 < 8; ++k8) {
            bf16x8 a = *(const bf16x8*)(&hb[(mt * 16 + l16) * 264 + k8 * 32 + l4 * 8]);
            bf16x8 b = *(const bf16x8*)(W2T + (nt * 16 + l16) * 256 + k8 * 32 + l4 * 8);
            acc = __builtin_amdgcn_mfma_f32_16x16x32_bf16(a, b, acc, 0, 0, 0);
        }
#pragma unroll
        for (int r = 0; r < 4; ++r)
            t2[(size_t)(row0 + mt * 16 + l4 * 4 + r) * N_CLASS + nt * 16 + l16] = acc[r];
    }

    cg::this_grid().sync();   // all t2 rows visible device-wide

    // ---- phase C: out = log_softmax(A @ t2) for this block's 32 nodes ----
    {
#pragma unroll
        for (int j = 0; j < 4; ++j) {
            const int n    = w * 4 + j;              // local node 0..31
            const int node = row0 + n;
            const int base = node & ~(NODE_NUM - 1);
            const int* e = edge + (size_t)node * MAX_DEG;
            const unsigned int m = mk[n];
            float acc = 0.f;
#pragma unroll
            for (int k = 0; k < MAX_DEG; ++k) {
                if (m & (1u << k)) acc += t2[(size_t)(base + e[k]) * N_CLASS + l];
            }
            float mx = acc;
#pragma unroll
            for (int o = 32; o > 0; o >>= 1) mx = fmaxf(mx, __shfl_xor(mx, o, 64));
            float s = expf(acc - mx);
#pragma unroll
            for (int o = 32; o > 0; o >>= 1) s += __shfl_xor(s, o, 64);
            out[(size_t)node * N_CLASS + l] = acc - mx - logf(s);
        }
    }
}

// ---------------------------------------------------------------------------
extern "C" void kernel_launch(void* const* d_in, const int* in_sizes, int n_in,
                              void* d_out, int out_size, void* d_ws, size_t ws_size,
                              hipStream_t stream) {
    const float* x    = (const float*)d_in[0];
    const int*   edge = (const int*)d_in[1];
    const float* W1   = (const float*)d_in[2];
    const float* W2   = (const float*)d_in[3];
    float* out = (float*)d_out;

    char* ws = (char*)d_ws;
    short* W1T = (short*)(ws);                       // 64 KB
    short* W2T = (short*)(ws + (64 << 10));          // 32 KB
    float* t2  = (float*)(ws + (128 << 10));         // 2 MB

    void* args[] = {(void*)&x, (void*)&edge, (void*)&W1, (void*)&W2,
                    (void*)&W1T, (void*)&W2T, (void*)&t2, (void*)&out};
    hipLaunchCooperativeKernel((const void*)k_all, dim3(256), dim3(512),
                               args, 0, stream);
}

// Round 5
// 116.743 us; speedup vs baseline: 1.3648x; 1.3648x over previous
//
#include <hip/hip_runtime.h>
#include <math.h>

#define NNODES   8192
#define NODE_NUM 256
#define MAX_DEG  16
#define N_FEAT   128
#define N_HID    256
#define N_CLASS  64
#define NENV     32      // 8192 / 256 env blocks

#define XS_STRIDE 132    // bf16 shorts per xs/t2 row (128 + 4 pad -> bank spread)
#define AG_STRIDE 136    // agg row stride (2-way max on b128)
#define HB_STRIDE 264    // h row stride

typedef __attribute__((ext_vector_type(8))) short bf16x8;
typedef __attribute__((ext_vector_type(4))) short s16x4;
typedef __attribute__((ext_vector_type(4))) float f32x4;

// f32 -> bf16 round-to-nearest-even
static __device__ __forceinline__ short f2b(float f) {
    unsigned u = __float_as_uint(f);
    unsigned r = (u + 0x7fffu + ((u >> 16) & 1u)) >> 16;
    return (short)r;
}
static __device__ __forceinline__ float b2f(short s) {
    return __uint_as_float(((unsigned)(unsigned short)s) << 16);
}

// ---------------------------------------------------------------------------
// One workgroup per env block (256 nodes). 32 blocks x 512 threads. No global
// intermediates, no grid sync. MFMA 16x16x32 bf16 layouts (R3-verified):
//   A: lane l holds A[row=l&15][k=8*(l>>4)+j]
//   B: lane l holds B[k=8*(l>>4)+j][col=l&15]   (held in REGISTERS here)
//   C: reg r -> row=(l>>4)*4+r, col=l&15
// ---------------------------------------------------------------------------
__global__ __launch_bounds__(512) void k_gcn(const float* __restrict__ x,
                                             const int* __restrict__ edge,
                                             const float* __restrict__ W1,
                                             const float* __restrict__ W2,
                                             float* __restrict__ out) {
    __shared__ short        agg[NODE_NUM * AG_STRIDE];   // 69632 B
    __shared__ short        hb[32 * HB_STRIDE];          // 16896 B (per 32-row tile)
    __shared__ unsigned int mk[NODE_NUM];                // 1024 B
    __shared__ short        xst[NODE_NUM * XS_STRIDE];   // 67584 B; reused as t2s
    short* t2s = xst;   // xs is dead before first t2 write (syncs in between)

    const int blk  = blockIdx.x;           // env block 0..31
    const int row0 = blk * NODE_NUM;
    const int t    = threadIdx.x;
    const int w    = t >> 6, l = t & 63;
    const int l16  = l & 15, l4 = l >> 4;

    // ---- per-node dedup/validity mask (threads 0..255) ----
    if (t < NODE_NUM) {
        const int* e = edge + (size_t)(row0 + t) * MAX_DEG;
        int ids[MAX_DEG];
#pragma unroll
        for (int k = 0; k < MAX_DEG; ++k) ids[k] = e[k];
        unsigned m = 0;
#pragma unroll
        for (int k = 0; k < MAX_DEG; ++k) {
            bool skip = (ids[k] == -1);
#pragma unroll
            for (int q = 0; q < k; ++q) skip = skip || (ids[q] == ids[k]);
            if (!skip) m |= 1u << k;
        }
        mk[t] = m;
    }

    // ---- weight fragments -> registers (issued early; latency hides under
    //      the LDS staging/gather below). 16-lane groups read 64B lines. ----
    bf16x8 w1f[4][4];                       // GEMM1: nt=(w&3)*4+n, k4
    {
        const int ntb = (w & 3) * 4;
#pragma unroll
        for (int n = 0; n < 4; ++n)
#pragma unroll
            for (int k4 = 0; k4 < 4; ++k4) {
                const int col = (ntb + n) * 16 + l16;
                const int kb  = k4 * 32 + l4 * 8;
                bf16x8 v;
#pragma unroll
                for (int j = 0; j < 8; ++j) v[j] = f2b(W1[(kb + j) * N_HID + col]);
                w1f[n][k4] = v;
            }
    }
    bf16x8 w2f[8];                          // GEMM2: nt=w&3, k8
    {
        const int col = (w & 3) * 16 + l16;
#pragma unroll
        for (int k8 = 0; k8 < 8; ++k8) {
            const int kb = k8 * 32 + l4 * 8;
            bf16x8 v;
#pragma unroll
            for (int j = 0; j < 8; ++j) v[j] = f2b(W2[(kb + j) * N_CLASS + col]);
            w2f[k8] = v;
        }
    }

    // ---- stage x slice -> xs bf16 [256][132], coalesced float4 reads ----
    {
#pragma unroll
        for (int i = 0; i < 16; ++i) {
            const int chunk = i * 512 + t;           // 8192 float4 chunks
            const int r = chunk >> 5, c = chunk & 31;
            float4 v = *(const float4*)(x + (size_t)(row0 + r) * N_FEAT + c * 4);
            s16x4 p = {f2b(v.x), f2b(v.y), f2b(v.z), f2b(v.w)};
            *(s16x4*)(xst + r * XS_STRIDE + c * 4) = p;
        }
    }
    __syncthreads();

    // ---- gather-aggregate from LDS: agg[n] = sum_nbr xs[nb]  (binary adj) ----
    // 4 threads/row, 32 feats each, 2 row-passes.
    {
        const int qt = t & 3;                        // feat quarter
#pragma unroll
        for (int p = 0; p < 2; ++p) {
            const int r = (t >> 2) + p * 128;        // local row
            const int* e = edge + (size_t)(row0 + r) * MAX_DEG;
            const unsigned m = mk[r];
            float acc[32];
#pragma unroll
            for (int i = 0; i < 32; ++i) acc[i] = 0.f;
#pragma unroll
            for (int k = 0; k < MAX_DEG; ++k) {
                if (m & (1u << k)) {
                    const short* src = xst + e[k] * XS_STRIDE + qt * 32;
#pragma unroll
                    for (int c = 0; c < 4; ++c) {
                        bf16x8 v = *(const bf16x8*)(src + c * 8);
#pragma unroll
                        for (int j = 0; j < 8; ++j) acc[c * 8 + j] += b2f(v[j]);
                    }
                }
            }
            short* d = agg + r * AG_STRIDE + qt * 32;
#pragma unroll
            for (int c = 0; c < 4; ++c) {
                bf16x8 pk;
#pragma unroll
                for (int j = 0; j < 8; ++j) pk[j] = f2b(acc[c * 8 + j]);
                *(bf16x8*)(d + c * 8) = pk;
            }
        }
    }
    __syncthreads();

    // ---- per-32-row tile: MFMA GEMM1+relu -> hb ; MFMA GEMM2 -> t2s ----
    const int mt = w >> 2;                           // 0..1 (16-row half)
    const int ntc = w & 3;
#pragma unroll 1
    for (int tt = 0; tt < 8; ++tt) {
        const int rbase = tt * 32 + mt * 16;
        bf16x8 af[4];
#pragma unroll
        for (int k4 = 0; k4 < 4; ++k4)
            af[k4] = *(const bf16x8*)(agg + (rbase + l16) * AG_STRIDE + k4 * 32 + l4 * 8);
#pragma unroll
        for (int n = 0; n < 4; ++n) {
            f32x4 acc = {0.f, 0.f, 0.f, 0.f};
#pragma unroll
            for (int k4 = 0; k4 < 4; ++k4)
                acc = __builtin_amdgcn_mfma_f32_16x16x32_bf16(af[k4], w1f[n][k4], acc, 0, 0, 0);
#pragma unroll
            for (int r = 0; r < 4; ++r)
                hb[(mt * 16 + l4 * 4 + r) * HB_STRIDE + (ntc * 4 + n) * 16 + l16] =
                    f2b(fmaxf(acc[r], 0.f));
        }
        __syncthreads();
        {
            f32x4 acc = {0.f, 0.f, 0.f, 0.f};
#pragma unroll
            for (int k8 = 0; k8 < 8; ++k8) {
                bf16x8 a = *(const bf16x8*)(hb + (mt * 16 + l16) * HB_STRIDE + k8 * 32 + l4 * 8);
                acc = __builtin_amdgcn_mfma_f32_16x16x32_bf16(a, w2f[k8], acc, 0, 0, 0);
            }
#pragma unroll
            for (int r = 0; r < 4; ++r)
                t2s[(tt * 32 + mt * 16 + l4 * 4 + r) * XS_STRIDE + ntc * 16 + l16] =
                    f2b(acc[r]);
        }
        __syncthreads();
    }

    // ---- phase C: out = log_softmax(A @ t2) ; 8-lane group per node ----
    {
        const int g = l >> 3, mm = l & 7;            // group 0..7, member 0..7
#pragma unroll
        for (int p = 0; p < 4; ++p) {
            const int node = w * 32 + p * 8 + g;     // local node 0..255
            const int* e = edge + (size_t)(row0 + node) * MAX_DEG;
            const unsigned m = mk[node];
            float acc[8];
#pragma unroll
            for (int j = 0; j < 8; ++j) acc[j] = 0.f;
#pragma unroll
            for (int k = 0; k < MAX_DEG; ++k) {
                if (m & (1u << k)) {
                    bf16x8 v = *(const bf16x8*)(t2s + e[k] * XS_STRIDE + mm * 8);
#pragma unroll
                    for (int j = 0; j < 8; ++j) acc[j] += b2f(v[j]);
                }
            }
            float mx = acc[0];
#pragma unroll
            for (int j = 1; j < 8; ++j) mx = fmaxf(mx, acc[j]);
#pragma unroll
            for (int o = 1; o < 8; o <<= 1) mx = fmaxf(mx, __shfl_xor(mx, o, 64));
            float s = 0.f;
#pragma unroll
            for (int j = 0; j < 8; ++j) s += expf(acc[j] - mx);
#pragma unroll
            for (int o = 1; o < 8; o <<= 1) s += __shfl_xor(s, o, 64);
            const float lse = mx + logf(s);
            float* op = out + (size_t)(row0 + node) * N_CLASS + mm * 8;
            float4 o0 = {acc[0] - lse, acc[1] - lse, acc[2] - lse, acc[3] - lse};
            float4 o1 = {acc[4] - lse, acc[5] - lse, acc[6] - lse, acc[7] - lse};
            *(float4*)(op)     = o0;
            *(float4*)(op + 4) = o1;
        }
    }
}

// ---------------------------------------------------------------------------
extern "C" void kernel_launch(void* const* d_in, const int* in_sizes, int n_in,
                              void* d_out, int out_size, void* d_ws, size_t ws_size,
                              hipStream_t stream) {
    const float* x    = (const float*)d_in[0];
    const int*   edge = (const int*)d_in[1];
    const float* W1   = (const float*)d_in[2];
    const float* W2   = (const float*)d_in[3];
    float* out = (float*)d_out;

    k_gcn<<<NENV, 512, 0, stream>>>(x, edge, W1, W2, out);
}

// Round 6
// 79.219 us; speedup vs baseline: 2.0112x; 1.4737x over previous
//
#include <hip/hip_runtime.h>
#include <math.h>

#define NNODES   8192
#define NODE_NUM 256
#define MAX_DEG  16
#define N_FEAT   128
#define N_HID    256
#define N_CLASS  64

#define AG_STRIDE 136    // agg row stride (shorts)
#define HB_STRIDE 264    // h row stride (shorts)

typedef __attribute__((ext_vector_type(8))) short bf16x8;
typedef __attribute__((ext_vector_type(4))) float f32x4;

// f32 -> bf16 round-to-nearest-even
static __device__ __forceinline__ short f2b(float f) {
    unsigned u = __float_as_uint(f);
    unsigned r = (u + 0x7fffu + ((u >> 16) & 1u)) >> 16;
    return (short)r;
}

// ---------------------------------------------------------------------------
// K1: 256 WGs x 512 thr; each WG owns 32 rows.
//   - W1/W2 -> bf16 MFMA B-fragments in registers (issued first, L2-resident)
//   - gather-aggregate x rows from global (L2), dedup mask inline -> agg LDS
//   - MFMA GEMM1+relu -> hb LDS ; MFMA GEMM2 -> t2 f32 (ws)
// MFMA 16x16x32 bf16 layouts (R3/R5-verified):
//   A: lane l holds A[row=l&15][k=8*(l>>4)+j]
//   B: lane l holds B[k=8*(l>>4)+j][col=l&15]
//   C: reg r -> row=(l>>4)*4+r, col=l&15
// ---------------------------------------------------------------------------
__global__ __launch_bounds__(512) void k_main(const float* __restrict__ x,
                                              const int* __restrict__ edge,
                                              const float* __restrict__ W1,
                                              const float* __restrict__ W2,
                                              unsigned int* __restrict__ maskw,
                                              float* __restrict__ t2) {
    __shared__ short agg[32 * AG_STRIDE];   // 8704 B
    __shared__ short hb[32 * HB_STRIDE];    // 16896 B

    const int bid  = blockIdx.x;
    const int work = (bid & 7) * 32 + (bid >> 3);   // XCD-bijective swizzle
    const int row0 = work * 32;
    const int t    = threadIdx.x;
    const int w    = t >> 6, l = t & 63;
    const int l16  = l & 15, l4 = l >> 4;

    // ---- weight fragments -> registers (no deps; latency hides under gather)
    bf16x8 w1f[4][4];                       // GEMM1: nt=(w&3)*4+n, k4
    {
        const int ntb = (w & 3) * 4;
#pragma unroll
        for (int n = 0; n < 4; ++n)
#pragma unroll
            for (int k4 = 0; k4 < 4; ++k4) {
                const int col = (ntb + n) * 16 + l16;
                const int kb  = k4 * 32 + l4 * 8;
                bf16x8 v;
#pragma unroll
                for (int j = 0; j < 8; ++j) v[j] = f2b(W1[(kb + j) * N_HID + col]);
                w1f[n][k4] = v;
            }
    }
    bf16x8 w2f[8];                          // GEMM2: nt=w&3, k8
    {
        const int col = (w & 3) * 16 + l16;
#pragma unroll
        for (int k8 = 0; k8 < 8; ++k8) {
            const int kb = k8 * 32 + l4 * 8;
            bf16x8 v;
#pragma unroll
            for (int j = 0; j < 8; ++j) v[j] = f2b(W2[(kb + j) * N_CLASS + col]);
            w2f[k8] = v;
        }
    }

    // ---- gather-aggregate from global x; dedup mask recomputed inline ----
    {
        const int r = t >> 4, c = t & 15;            // row 0..31, 8-feat chunk
        const int node = row0 + r;
        const int base = node & ~(NODE_NUM - 1);
        const int* e = edge + (size_t)node * MAX_DEG;
        int ids[MAX_DEG];
#pragma unroll
        for (int k = 0; k < MAX_DEG; ++k) ids[k] = e[k];
        unsigned m = 0;
#pragma unroll
        for (int k = 0; k < MAX_DEG; ++k) {
            bool skip = (ids[k] == -1);
#pragma unroll
            for (int q = 0; q < k; ++q) skip = skip || (ids[q] == ids[k]);
            if (!skip) m |= 1u << k;
        }
        if (c == 0) maskw[node] = m;                 // for K2
        float a[8] = {0, 0, 0, 0, 0, 0, 0, 0};
#pragma unroll
        for (int k = 0; k < MAX_DEG; ++k) {
            if (m & (1u << k)) {
                const float* rowp = x + (size_t)(base + ids[k]) * N_FEAT + c * 8;
                float4 v0 = *(const float4*)(rowp);
                float4 v1 = *(const float4*)(rowp + 4);
                a[0] += v0.x; a[1] += v0.y; a[2] += v0.z; a[3] += v0.w;
                a[4] += v1.x; a[5] += v1.y; a[6] += v1.z; a[7] += v1.w;
            }
        }
        bf16x8 p;
#pragma unroll
        for (int j = 0; j < 8; ++j) p[j] = f2b(a[j]);
        *(bf16x8*)(&agg[r * AG_STRIDE + c * 8]) = p;
    }
    __syncthreads();

    // ---- GEMM1 + relu -> hb ----
    const int mt = w >> 2, ntc = w & 3;              // 2M x 4N wave tiles
    {
        bf16x8 af[4];
#pragma unroll
        for (int k4 = 0; k4 < 4; ++k4)
            af[k4] = *(const bf16x8*)(&agg[(mt * 16 + l16) * AG_STRIDE + k4 * 32 + l4 * 8]);
#pragma unroll
        for (int n = 0; n < 4; ++n) {
            f32x4 acc = {0.f, 0.f, 0.f, 0.f};
#pragma unroll
            for (int k4 = 0; k4 < 4; ++k4)
                acc = __builtin_amdgcn_mfma_f32_16x16x32_bf16(af[k4], w1f[n][k4], acc, 0, 0, 0);
#pragma unroll
            for (int r = 0; r < 4; ++r)
                hb[(mt * 16 + l4 * 4 + r) * HB_STRIDE + (ntc * 4 + n) * 16 + l16] =
                    f2b(fmaxf(acc[r], 0.f));
        }
    }
    __syncthreads();

    // ---- GEMM2 -> t2 (f32, global ws) ----
    {
        f32x4 acc = {0.f, 0.f, 0.f, 0.f};
#pragma unroll
        for (int k8 = 0; k8 < 8; ++k8) {
            bf16x8 a = *(const bf16x8*)(&hb[(mt * 16 + l16) * HB_STRIDE + k8 * 32 + l4 * 8]);
            acc = __builtin_amdgcn_mfma_f32_16x16x32_bf16(a, w2f[k8], acc, 0, 0, 0);
        }
#pragma unroll
        for (int r = 0; r < 4; ++r)
            t2[(size_t)(row0 + mt * 16 + l4 * 4 + r) * N_CLASS + ntc * 16 + l16] = acc[r];
    }
}

// ---------------------------------------------------------------------------
// K2: out = log_softmax(A @ t2). 256 WGs x 512 thr; 32 nodes/WG;
// 16 lanes per node, each owning 4 classes (float4).
// ---------------------------------------------------------------------------
__global__ __launch_bounds__(512) void k_final(const float* __restrict__ t2,
                                               const int* __restrict__ edge,
                                               const unsigned int* __restrict__ maskw,
                                               float* __restrict__ out) {
    const int bid  = blockIdx.x;
    const int work = (bid & 7) * 32 + (bid >> 3);
    const int row0 = work * 32;
    const int t    = threadIdx.x;
    const int r = t >> 4, c = t & 15;                // node 0..31, class quad
    const int node = row0 + r;
    const int base = node & ~(NODE_NUM - 1);
    const int* e = edge + (size_t)node * MAX_DEG;
    const unsigned m = maskw[node];

    float4 acc = {0.f, 0.f, 0.f, 0.f};
#pragma unroll
    for (int k = 0; k < MAX_DEG; ++k) {
        if (m & (1u << k)) {
            float4 v = *(const float4*)(t2 + (size_t)(base + e[k]) * N_CLASS + c * 4);
            acc.x += v.x; acc.y += v.y; acc.z += v.z; acc.w += v.w;
        }
    }
    // max / sum across the 16 lanes of this node (xor of lane bits 0..3)
    float mx = fmaxf(fmaxf(acc.x, acc.y), fmaxf(acc.z, acc.w));
#pragma unroll
    for (int o = 1; o < 16; o <<= 1) mx = fmaxf(mx, __shfl_xor(mx, o, 64));
    float s = expf(acc.x - mx) + expf(acc.y - mx) + expf(acc.z - mx) + expf(acc.w - mx);
#pragma unroll
    for (int o = 1; o < 16; o <<= 1) s += __shfl_xor(s, o, 64);
    const float lse = mx + logf(s);

    float4 o4 = {acc.x - lse, acc.y - lse, acc.z - lse, acc.w - lse};
    *(float4*)(out + (size_t)node * N_CLASS + c * 4) = o4;
}

// ---------------------------------------------------------------------------
extern "C" void kernel_launch(void* const* d_in, const int* in_sizes, int n_in,
                              void* d_out, int out_size, void* d_ws, size_t ws_size,
                              hipStream_t stream) {
    const float* x    = (const float*)d_in[0];
    const int*   edge = (const int*)d_in[1];
    const float* W1   = (const float*)d_in[2];
    const float* W2   = (const float*)d_in[3];
    float* out = (float*)d_out;

    char* ws = (char*)d_ws;
    unsigned int* maskw = (unsigned int*)ws;             // 32 KB
    float*        t2    = (float*)(ws + (64 << 10));     // 2 MB

    k_main <<<NNODES / 32, 512, 0, stream>>>(x, edge, W1, W2, maskw, t2);
    k_final<<<NNODES / 32, 512, 0, stream>>>(t2, edge, maskw, out);
}

// Round 8
// 77.257 us; speedup vs baseline: 2.0623x; 1.0254x over previous
//
#include <hip/hip_runtime.h>
#include <math.h>

#define NNODES   8192
#define NODE_NUM 256
#define MAX_DEG  16
#define N_FEAT   128
#define N_HID    256
#define N_CLASS  64

#define AG_STRIDE 136    // agg row stride (shorts)
#define HB_STRIDE 264    // h row stride (shorts)

typedef __attribute__((ext_vector_type(8))) short bf16x8;
typedef __attribute__((ext_vector_type(4))) float f32x4;

// f32 -> bf16 round-to-nearest-even
static __device__ __forceinline__ short f2b(float f) {
    unsigned u = __float_as_uint(f);
    unsigned r = (u + 0x7fffu + ((u >> 16) & 1u)) >> 16;
    return (short)r;
}
static __device__ __forceinline__ float b2f(short s) {
    return __uint_as_float(((unsigned)(unsigned short)s) << 16);
}

// ---------------------------------------------------------------------------
// K0: one-shot prep. 256 WGs x 256 thr, one output element per thread.
//  g <  8192 : dedup/validity mask per node
//  g < 40960 : W1T pre-swizzled bf16 fragment store
//              W1T[((nt*4+k4)*64 + l)*8 + j] = bf16(W1[(k4*32+(l>>4)*8+j)*256 + nt*16+(l&15)])
//  g < 57344 : W2T likewise
//              W2T[((nt*8+k8)*64 + l)*8 + j] = bf16(W2[(k8*32+(l>>4)*8+j)*64 + nt*16+(l&15)])
// ---------------------------------------------------------------------------
__global__ __launch_bounds__(256) void k_prep(const int* __restrict__ edge,
                                              const float* __restrict__ W1,
                                              const float* __restrict__ W2,
                                              unsigned int* __restrict__ maskw,
                                              short* __restrict__ W1T,
                                              short* __restrict__ W2T) {
    const int g = blockIdx.x * 256 + threadIdx.x;
    if (g < 8192) {
        const int* e = edge + (size_t)g * MAX_DEG;
        int ids[MAX_DEG];
#pragma unroll
        for (int k = 0; k < MAX_DEG; ++k) ids[k] = e[k];
        unsigned m = 0;
#pragma unroll
        for (int k = 0; k < MAX_DEG; ++k) {
            bool skip = (ids[k] == -1);
#pragma unroll
            for (int q = 0; q < k; ++q) skip = skip || (ids[q] == ids[k]);
            if (!skip) m |= 1u << k;
        }
        maskw[g] = m;
    } else if (g < 40960) {
        const int o = g - 8192;
        const int j = o & 7, l = (o >> 3) & 63, k4 = (o >> 9) & 3, nt = (o >> 11) & 15;
        W1T[o] = f2b(W1[(k4 * 32 + (l >> 4) * 8 + j) * N_HID + nt * 16 + (l & 15)]);
    } else if (g < 57344) {
        const int o = g - 40960;
        const int j = o & 7, l = (o >> 3) & 63, k8 = (o >> 9) & 7, nt = (o >> 12) & 3;
        W2T[o] = f2b(W2[(k8 * 32 + (l >> 4) * 8 + j) * N_CLASS + nt * 16 + (l & 15)]);
    }
}

// ---------------------------------------------------------------------------
// K1: 256 WGs x 512 thr; each WG owns 32 rows.
//   - weight fragments: 24 coalesced b128 loads (pre-swizzled by K0)
//   - gather-aggregate x rows from global (L2) -> agg LDS (bf16)
//   - MFMA GEMM1+relu -> hb LDS ; MFMA GEMM2 -> t2 bf16 (ws)
// MFMA 16x16x32 bf16 layouts (R3/R5/R6-verified):
//   A: lane l holds A[row=l&15][k=8*(l>>4)+j]
//   B: lane l holds B[k=8*(l>>4)+j][col=l&15]
//   C: reg r -> row=(l>>4)*4+r, col=l&15
// ---------------------------------------------------------------------------
__global__ __launch_bounds__(512) void k_main(const float* __restrict__ x,
                                              const int* __restrict__ edge,
                                              const unsigned int* __restrict__ maskw,
                                              const short* __restrict__ W1T,
                                              const short* __restrict__ W2T,
                                              short* __restrict__ t2b) {
    __shared__ short agg[32 * AG_STRIDE];   // 8704 B
    __shared__ short hb[32 * HB_STRIDE];    // 16896 B

    const int bid  = blockIdx.x;
    const int work = (bid & 7) * 32 + (bid >> 3);   // XCD-bijective swizzle
    const int row0 = work * 32;
    const int t    = threadIdx.x;
    const int w    = t >> 6, l = t & 63;
    const int l16  = l & 15, l4 = l >> 4;

    // ---- weight fragments: coalesced vector loads, hidden under gather ----
    bf16x8 w1f[4][4];
    {
        const int ntb = (w & 3) * 4;
#pragma unroll
        for (int n = 0; n < 4; ++n)
#pragma unroll
            for (int k4 = 0; k4 < 4; ++k4)
                w1f[n][k4] = *(const bf16x8*)(W1T + ((size_t)((ntb + n) * 4 + k4) * 64 + l) * 8);
    }
    bf16x8 w2f[8];
    {
        const int nt = w & 3;
#pragma unroll
        for (int k8 = 0; k8 < 8; ++k8)
            w2f[k8] = *(const bf16x8*)(W2T + ((size_t)(nt * 8 + k8) * 64 + l) * 8);
    }

    // ---- gather-aggregate from global x (mask precomputed) ----
    {
        const int r = t >> 4, c = t & 15;            // row 0..31, 8-feat chunk
        const int node = row0 + r;
        const int base = node & ~(NODE_NUM - 1);
        const int* e = edge + (size_t)node * MAX_DEG;
        const unsigned m = maskw[node];
        float a[8] = {0, 0, 0, 0, 0, 0, 0, 0};
#pragma unroll
        for (int k = 0; k < MAX_DEG; ++k) {
            if (m & (1u << k)) {
                const float* rowp = x + (size_t)(base + e[k]) * N_FEAT + c * 8;
                float4 v0 = *(const float4*)(rowp);
                float4 v1 = *(const float4*)(rowp + 4);
                a[0] += v0.x; a[1] += v0.y; a[2] += v0.z; a[3] += v0.w;
                a[4] += v1.x; a[5] += v1.y; a[6] += v1.z; a[7] += v1.w;
            }
        }
        bf16x8 p;
#pragma unroll
        for (int j = 0; j < 8; ++j) p[j] = f2b(a[j]);
        *(bf16x8*)(&agg[r * AG_STRIDE + c * 8]) = p;
    }
    __syncthreads();

    // ---- GEMM1 + relu -> hb ----
    const int mt = w >> 2, ntc = w & 3;              // 2M x 4N wave tiles
    {
        bf16x8 af[4];
#pragma unroll
        for (int k4 = 0; k4 < 4; ++k4)
            af[k4] = *(const bf16x8*)(&agg[(mt * 16 + l16) * AG_STRIDE + k4 * 32 + l4 * 8]);
#pragma unroll
        for (int n = 0; n < 4; ++n) {
            f32x4 acc = {0.f, 0.f, 0.f, 0.f};
#pragma unroll
            for (int k4 = 0; k4 < 4; ++k4)
                acc = __builtin_amdgcn_mfma_f32_16x16x32_bf16(af[k4], w1f[n][k4], acc, 0, 0, 0);
#pragma unroll
            for (int r = 0; r < 4; ++r)
                hb[(mt * 16 + l4 * 4 + r) * HB_STRIDE + (ntc * 4 + n) * 16 + l16] =
                    f2b(fmaxf(acc[r], 0.f));
        }
    }
    __syncthreads();

    // ---- GEMM2 -> t2 (bf16, global ws) ----
    {
        f32x4 acc = {0.f, 0.f, 0.f, 0.f};
#pragma unroll
        for (int k8 = 0; k8 < 8; ++k8) {
            bf16x8 a = *(const bf16x8*)(&hb[(mt * 16 + l16) * HB_STRIDE + k8 * 32 + l4 * 8]);
            acc = __builtin_amdgcn_mfma_f32_16x16x32_bf16(a, w2f[k8], acc, 0, 0, 0);
        }
#pragma unroll
        for (int r = 0; r < 4; ++r)
            t2b[(size_t)(row0 + mt * 16 + l4 * 4 + r) * N_CLASS + ntc * 16 + l16] = f2b(acc[r]);
    }
}

// ---------------------------------------------------------------------------
// K2: out = log_softmax(A @ t2). 256 WGs x 256 thr; 32 nodes/WG;
// 8 lanes per node, each owning 8 classes (one bf16x8 per neighbor row).
// ---------------------------------------------------------------------------
__global__ __launch_bounds__(256) void k_final(const short* __restrict__ t2b,
                                               const int* __restrict__ edge,
                                               const unsigned int* __restrict__ maskw,
                                               float* __restrict__ out) {
    const int bid  = blockIdx.x;
    const int work = (bid & 7) * 32 + (bid >> 3);
    const int row0 = work * 32;
    const int t    = threadIdx.x;
    const int r = t >> 3, mm = t & 7;                // node 0..31, class octet
    const int node = row0 + r;
    const int base = node & ~(NODE_NUM - 1);
    const int* e = edge + (size_t)node * MAX_DEG;
    const unsigned m = maskw[node];

    float acc[8] = {0, 0, 0, 0, 0, 0, 0, 0};
#pragma unroll
    for (int k = 0; k < MAX_DEG; ++k) {
        if (m & (1u << k)) {
            bf16x8 v = *(const bf16x8*)(t2b + (size_t)(base + e[k]) * N_CLASS + mm * 8);
#pragma unroll
            for (int j = 0; j < 8; ++j) acc[j] += b2f(v[j]);
        }
    }
    float mx = acc[0];
#pragma unroll
    for (int j = 1; j < 8; ++j) mx = fmaxf(mx, acc[j]);
#pragma unroll
    for (int o = 1; o < 8; o <<= 1) mx = fmaxf(mx, __shfl_xor(mx, o, 64));
    float s = 0.f;
#pragma unroll
    for (int j = 0; j < 8; ++j) s += expf(acc[j] - mx);
#pragma unroll
    for (int o = 1; o < 8; o <<= 1) s += __shfl_xor(s, o, 64);
    const float lse = mx + logf(s);

    float* op = out + (size_t)node * N_CLASS + mm * 8;
    float4 o0 = {acc[0] - lse, acc[1] - lse, acc[2] - lse, acc[3] - lse};
    float4 o1 = {acc[4] - lse, acc[5] - lse, acc[6] - lse, acc[7] - lse};
    *(float4*)(op)     = o0;
    *(float4*)(op + 4) = o1;
}

// ---------------------------------------------------------------------------
extern "C" void kernel_launch(void* const* d_in, const int* in_sizes, int n_in,
                              void* d_out, int out_size, void* d_ws, size_t ws_size,
                              hipStream_t stream) {
    const float* x    = (const float*)d_in[0];
    const int*   edge = (const int*)d_in[1];
    const float* W1   = (const float*)d_in[2];
    const float* W2   = (const float*)d_in[3];
    float* out = (float*)d_out;

    char* ws = (char*)d_ws;
    unsigned int* maskw = (unsigned int*)ws;             // 32 KB
    short*        W1T   = (short*)(ws + (32 << 10));     // 64 KB
    short*        W2T   = (short*)(ws + (96 << 10));     // 32 KB
    short*        t2b   = (short*)(ws + (128 << 10));    // 1 MB

    k_prep <<<256,         256, 0, stream>>>(edge, W1, W2, maskw, W1T, W2T);
    k_main <<<NNODES / 32, 512, 0, stream>>>(x, edge, maskw, W1T, W2T, t2b);
    k_final<<<NNODES / 32, 256, 0, stream>>>(t2b, edge, maskw, out);
}